// Round 1
// baseline (1483.239 us; speedup 1.0000x reference)
//
#include <hip/hip_runtime.h>
#include <hip/hip_bf16.h>
#include <stdint.h>
#include <stddef.h>

#define OUT_F  11008
#define IN_F   4096
#define M_ROWS 8192

typedef __bf16 bf16;
typedef __attribute__((ext_vector_type(8))) __bf16 bf16x8;
typedef __attribute__((ext_vector_type(4))) float floatx4;

__device__ const float NF4_TAB[16] = {
    -1.0f, -0.6961928009986877f, -0.5250730514526367f, -0.39491748809814453f,
    -0.28444138169288635f, -0.18477343022823334f, -0.09105003625154495f, 0.0f,
    0.07958029955625534f, 0.16093020141124725f, 0.24611230194568634f,
    0.33791524171829224f, 0.44070982933044434f, 0.5626170039176941f,
    0.7229568362236023f, 1.0f};

// ---------------------------------------------------------------- cvt x: fp32 -> bf16
__global__ __launch_bounds__(256) void cvt_x_kernel(const float* __restrict__ x,
                                                    bf16* __restrict__ xb) {
    size_t t = (size_t)blockIdx.x * 256 + threadIdx.x;   // 8 elements per thread
    const float4* xv = (const float4*)x;
    float4 a = xv[2 * t];
    float4 b = xv[2 * t + 1];
    bf16x8 o;
    o[0] = (bf16)a.x; o[1] = (bf16)a.y; o[2] = (bf16)a.z; o[3] = (bf16)a.w;
    o[4] = (bf16)b.x; o[5] = (bf16)b.y; o[6] = (bf16)b.z; o[7] = (bf16)b.w;
    *(bf16x8*)(xb + 8 * t) = o;
}

// ------------------------------------------------- dequant: NF4 idx * scale -> bf16 W
__global__ __launch_bounds__(256) void dequant_kernel(const int* __restrict__ q,
                                                      const float* __restrict__ sc,
                                                      bf16* __restrict__ wb) {
    __shared__ float tab[16];
    if (threadIdx.x < 16) tab[threadIdx.x] = NF4_TAB[threadIdx.x];
    __syncthreads();
    size_t t = (size_t)blockIdx.x * 256 + threadIdx.x;   // 8 elements per thread
    const int4* qv = (const int4*)q;
    int4 a = qv[2 * t];
    int4 b = qv[2 * t + 1];
    float s = sc[t >> 4];   // group = (8t)/128 = t/16 ; 8t%128 <= 120 so uniform over 8
    bf16x8 o;
    o[0] = (bf16)(tab[a.x & 15] * s); o[1] = (bf16)(tab[a.y & 15] * s);
    o[2] = (bf16)(tab[a.z & 15] * s); o[3] = (bf16)(tab[a.w & 15] * s);
    o[4] = (bf16)(tab[b.x & 15] * s); o[5] = (bf16)(tab[b.y & 15] * s);
    o[6] = (bf16)(tab[b.z & 15] * s); o[7] = (bf16)(tab[b.w & 15] * s);
    *(bf16x8*)(wb + 8 * t) = o;
}

// ---------------------------------------------------------------- MFMA GEMM + bias
// C[M,N] = A[M,K] * B[N,K]^T + bias ; A=x bf16, B=W bf16 (both K-contiguous)
#define BM 128
#define BN 128
#define BK 32

static __device__ __forceinline__ void gload_lds16(const void* g, void* l) {
    __builtin_amdgcn_global_load_lds((const __attribute__((address_space(1))) void*)g,
                                     (__attribute__((address_space(3))) void*)l,
                                     16, 0, 0);
}

__global__ __launch_bounds__(256) void gemm_bias_kernel(const bf16* __restrict__ A,
                                                        const bf16* __restrict__ B,
                                                        const float* __restrict__ bias,
                                                        float* __restrict__ C) {
    __shared__ bf16 sA[BM * BK];   // 8 KB, row-major [row][k], stride 32 (NO pad:
    __shared__ bf16 sB[BN * BK];   // global_load_lds dest is base + lane*16)

    const int tid  = threadIdx.x;
    const int wv   = tid >> 6;        // wave 0..3
    const int lane = tid & 63;
    const int quad = lane >> 4;       // 0..3
    const int l16  = lane & 15;

    const int bm = blockIdx.y * BM;
    const int bn = blockIdx.x * BN;

    // staging: each lane loads 16 B (8 bf16); wave w covers 16 rows per issue
    const int srow = lane >> 2;           // 0..15 row within wave chunk
    const int scol = (lane & 3) * 8;      // k element offset

    const int wm = (wv >> 1) * 64;        // wave's 64x64 quadrant
    const int wn = (wv & 1) * 64;

    floatx4 acc[4][4] = {};

    const bf16* Abase = A + (size_t)bm * IN_F;
    const bf16* Bbase = B + (size_t)bn * IN_F;

    for (int k0 = 0; k0 < IN_F; k0 += BK) {
#pragma unroll
        for (int i = 0; i < 2; ++i) {   // A tile: 2 issues x 64 rows
            int row = i * 64 + wv * 16 + srow;
            gload_lds16(Abase + (size_t)row * IN_F + k0 + scol,
                        &sA[(i * 64 + wv * 16) * BK]);
        }
#pragma unroll
        for (int i = 0; i < 2; ++i) {   // B tile
            int row = i * 64 + wv * 16 + srow;
            gload_lds16(Bbase + (size_t)row * IN_F + k0 + scol,
                        &sB[(i * 64 + wv * 16) * BK]);
        }
        __syncthreads();   // drains vmcnt (global_load_lds) before LDS reads

        bf16x8 af[4], bfr[4];
#pragma unroll
        for (int mt = 0; mt < 4; ++mt)
            af[mt] = *(const bf16x8*)&sA[(wm + mt * 16 + l16) * BK + quad * 8];
#pragma unroll
        for (int nt = 0; nt < 4; ++nt)
            bfr[nt] = *(const bf16x8*)&sB[(wn + nt * 16 + l16) * BK + quad * 8];
#pragma unroll
        for (int mt = 0; mt < 4; ++mt)
#pragma unroll
            for (int nt = 0; nt < 4; ++nt)
                acc[mt][nt] = __builtin_amdgcn_mfma_f32_16x16x32_bf16(
                    af[mt], bfr[nt], acc[mt][nt], 0, 0, 0);
        __syncthreads();
    }

    // epilogue: C/D layout col=lane&15, row=quad*4+reg  [m89-verified]
#pragma unroll
    for (int nt = 0; nt < 4; ++nt) {
        int col = bn + wn + nt * 16 + l16;
        float bv = bias[col];
#pragma unroll
        for (int mt = 0; mt < 4; ++mt) {
            int row0 = bm + wm + mt * 16 + quad * 4;
#pragma unroll
            for (int r = 0; r < 4; ++r)
                C[(size_t)(row0 + r) * OUT_F + col] = acc[mt][nt][r] + bv;
        }
    }
}

// ------------------------------------- fallback (no workspace): fp32 tiled GEMM
#define FBM 64
#define FBN 64
#define FBK 64
__global__ __launch_bounds__(256) void fallback_gemm(const float* __restrict__ x,
                                                     const int* __restrict__ q,
                                                     const float* __restrict__ sc,
                                                     const float* __restrict__ bias,
                                                     float* __restrict__ out) {
    __shared__ float sA[FBM][FBK + 1];
    __shared__ float sB[FBN][FBK + 1];
    const int tx = threadIdx.x & 15, ty = threadIdx.x >> 4;
    const int bm = blockIdx.y * FBM, bn = blockIdx.x * FBN;
    float acc[4][4] = {};
    for (int k0 = 0; k0 < IN_F; k0 += FBK) {
        for (int i = threadIdx.x; i < FBM * (FBK / 4); i += 256) {
            int r = i / (FBK / 4), c4 = (i % (FBK / 4)) * 4;
            float4 v = *(const float4*)&x[(size_t)(bm + r) * IN_F + k0 + c4];
            sA[r][c4] = v.x; sA[r][c4 + 1] = v.y; sA[r][c4 + 2] = v.z; sA[r][c4 + 3] = v.w;
            size_t fi = (size_t)(bn + r) * IN_F + k0 + c4;
            int4 qv = *(const int4*)&q[fi];
            float s = sc[fi >> 7];
            sB[r][c4]     = NF4_TAB[qv.x & 15] * s;
            sB[r][c4 + 1] = NF4_TAB[qv.y & 15] * s;
            sB[r][c4 + 2] = NF4_TAB[qv.z & 15] * s;
            sB[r][c4 + 3] = NF4_TAB[qv.w & 15] * s;
        }
        __syncthreads();
        for (int k = 0; k < FBK; ++k) {
            float av[4], bvv[4];
#pragma unroll
            for (int i = 0; i < 4; ++i) av[i] = sA[ty * 4 + i][k];
#pragma unroll
            for (int j = 0; j < 4; ++j) bvv[j] = sB[tx * 4 + j][k];
#pragma unroll
            for (int i = 0; i < 4; ++i)
#pragma unroll
                for (int j = 0; j < 4; ++j) acc[i][j] += av[i] * bvv[j];
        }
        __syncthreads();
    }
#pragma unroll
    for (int i = 0; i < 4; ++i)
#pragma unroll
        for (int j = 0; j < 4; ++j)
            out[(size_t)(bm + ty * 4 + i) * OUT_F + bn + tx * 4 + j] =
                acc[i][j] + bias[bn + tx * 4 + j];
}

// ---------------------------------------------------------------- launch
extern "C" void kernel_launch(void* const* d_in, const int* in_sizes, int n_in,
                              void* d_out, int out_size, void* d_ws, size_t ws_size,
                              hipStream_t stream) {
    const float* x    = (const float*)d_in[0];
    const int*   q    = (const int*)d_in[1];
    const float* sc   = (const float*)d_in[2];
    const float* bias = (const float*)d_in[3];
    float* out = (float*)d_out;

    const size_t xb_bytes = (size_t)M_ROWS * IN_F * sizeof(bf16);   // 67.1 MB
    const size_t wb_bytes = (size_t)OUT_F * IN_F * sizeof(bf16);    // 90.2 MB

    if (ws_size >= xb_bytes + wb_bytes) {
        bf16* xb = (bf16*)d_ws;
        bf16* wb = (bf16*)((char*)d_ws + xb_bytes);
        cvt_x_kernel<<<(M_ROWS * IN_F) / (8 * 256), 256, 0, stream>>>(x, xb);
        dequant_kernel<<<(OUT_F * IN_F) / (8 * 256), 256, 0, stream>>>(q, sc, wb);
        gemm_bias_kernel<<<dim3(OUT_F / BN, M_ROWS / BM), 256, 0, stream>>>(xb, wb, bias, out);
    } else {
        fallback_gemm<<<dim3(OUT_F / FBN, M_ROWS / FBM), 256, 0, stream>>>(x, q, sc, bias, out);
    }
}